// Round 7
// baseline (10130.186 us; speedup 1.0000x reference)
//
#include <hip/hip_runtime.h>

// SNN-MNIST forward + STDP, MI355X persistent cooperative kernel.
// Round 11: cache-the-coherent-data. FETCH_SIZE showed 13.9 MB/step from
// HBM == the Wt gather footprint: sc1 LOADS bypass L2/L3 reuse, so 1.6 MB
// of weights was re-fetched from memory 200x/step. Change: cross-block
// LOADS become plain cached loads; correctness preserved by an agent-scope
// ACQUIRE fence (buffer_inv: invalidates clean L1/L2 lines, preserves
// dirty private lines) at the tail of every grid barrier. Cross-block
// STORES stay sc1 write-through (proven). Also: gather back to 16-deep
// (round-10 datum: capped 48 is slower), 1e-3 folded out of the phase-2
// inner loop (ref scales after the sum too). Keeps round-10 belts:
// __launch_bounds__(256,2) + coop-launch rc check.

#define T_STEPS 200
#define BATCH   256
#define INQ     784
#define NOUT    400
#define NP      512
#define GRID    256
#define NTHR    256

// ws layout (float offsets)
#define OFF_WT    0            // Wt [785][512] (row 784 = zero pad for gather)
#define OFF_SYN   401920       // syn [256][512]         (block-private)
#define OFF_MEM   532992       // mem [256][512]         (block-private)
#define OFF_SPPO  664064       // interleaved (spk,post): [256][1024]
#define OFF_TRA   926208       // trA [256][784]
#define OFF_TRB   1126912      // trB [256][784]
#define OFF_WIN   1327616      // int win[256]           (block-private)
#define OFF_ANY   1327872      // u32 anyspk[2][256]     (sc1, ping-pong)
#define OFF_BARF  1328384      // u32 barf[256]: all-to-all barrier flags
#define WS_FLOATS 1332224

// ---- agent-coherent (sc1) access helpers (stores + barrier/flag loads) ----
__device__ __forceinline__ float ld_coh(const float* p) {
  return __hip_atomic_load(p, __ATOMIC_RELAXED, __HIP_MEMORY_SCOPE_AGENT);
}
__device__ __forceinline__ void st_coh(float* p, float v) {
  __hip_atomic_store(p, v, __ATOMIC_RELAXED, __HIP_MEMORY_SCOPE_AGENT);
}
__device__ __forceinline__ void st_coh2(float* p, float2 v) {
  union { unsigned long long u; float2 f; } c; c.f = v;
  __hip_atomic_store((unsigned long long*)p, c.u, __ATOMIC_RELAXED,
                     __HIP_MEMORY_SCOPE_AGENT);
}
__device__ __forceinline__ void st_cohu(unsigned* p, unsigned v) {
  __hip_atomic_store(p, v, __ATOMIC_RELAXED, __HIP_MEMORY_SCOPE_AGENT);
}
__device__ __forceinline__ unsigned long long ld_cohu64(const unsigned long long* p) {
  return __hip_atomic_load(p, __ATOMIC_RELAXED, __HIP_MEMORY_SCOPE_AGENT);
}

__device__ __forceinline__ void gl_lds16(const float* g, float* l) {  // cached
  __builtin_amdgcn_global_load_lds(
      (const __attribute__((address_space(1))) void*)g,
      (__attribute__((address_space(3))) void*)l, 16, 0, 0);
}

// All-to-all flag barrier + agent acquire fence. Arrival: each block STORES
// its own flag. Release: wave 0 polls all 256 flags. Tail: acquire fence
// (s_waitcnt + buffer_inv) invalidates clean L1/L2 lines so subsequent
// PLAIN cached loads observe all pre-barrier sc1 write-through stores.
__device__ __forceinline__ void gbar(unsigned* barf, unsigned k, int blk) {
  __syncthreads();
  if (threadIdx.x == 0)
    st_cohu(barf + blk, k);
  if (threadIdx.x < 64) {
    const unsigned long long* p =
        (const unsigned long long*)barf + (threadIdx.x << 1);
    for (;;) {
      unsigned long long a = ld_cohu64(p);
      unsigned long long bq = ld_cohu64(p + 1);
      unsigned m0 = (unsigned)a, m1 = (unsigned)(a >> 32);
      unsigned m2 = (unsigned)bq, m3 = (unsigned)(bq >> 32);
      unsigned mn = m0 < m1 ? m0 : m1;
      unsigned mo = m2 < m3 ? m2 : m3;
      mn = mn < mo ? mn : mo;
      if (__all(mn >= k)) break;
      __builtin_amdgcn_s_sleep(1);
    }
  }
  __syncthreads();
  __builtin_amdgcn_fence(__ATOMIC_ACQUIRE, "agent");   // buffer_inv
}

__global__ void __launch_bounds__(NTHR, 2) snn_kernel(
    const float* __restrict__ img,   // [200][256][784]
    const float* __restrict__ Win,   // [400][784]
    float* __restrict__ out,         // mem_rec | spk_rec | W_final
    float* ws)
{
  float* Wt    = ws + OFF_WT;
  float* syn   = ws + OFF_SYN;
  float* mem   = ws + OFF_MEM;
  float* sppo  = ws + OFF_SPPO;
  float* trA   = ws + OFF_TRA;
  float* trB   = ws + OFF_TRB;
  int*   win   = (int*)(ws + OFF_WIN);
  unsigned* anyspk = (unsigned*)(ws + OFF_ANY);
  unsigned* barf   = (unsigned*)(ws + OFF_BARF);

  float* mem_rec = out;
  float* spk_rec = out + (size_t)T_STEPS * BATCH * NOUT;
  float* Wout    = out + (size_t)2 * T_STEPS * BATCH * NOUT;

  const int tid = threadIdx.x;
  const int blk = blockIdx.x;
  unsigned bt = 0;                    // barrier ordinal

  __shared__ float stg_tr[16384];     // tr  [256][64]  (persistent per step)
  __shared__ float stg_im[16384];     // img [256][64]  (persistent per step)
  __shared__ float stg_sp[2][2048];   // sppo chunk dbuf [32][64]
  __shared__ int s_list[816];
  __shared__ int s_cnt, s_any;
  __shared__ int s_red[4];

  // phase-2 tile geometry (also used for prefetch)
  const int p2w = tid >> 6, p2l = tid & 63;
  const int bi = blk / 13, bn = blk % 13;
  const int ib0 = bi * 64, nb0 = bn * 32;
  int icol = ib0 + (p2l & 15) * 4;
  if (icol > INQ - 4) icol = INQ - 4;           // clamp (garbage, unused)
  const int scol = 2 * nb0 + (p2l & 15) * 4;

  // ---- init: Wt[i][n] = Win[n][i], written coherently ----
  for (int e = blk * NTHR + tid; e < NOUT * INQ; e += GRID * NTHR) {
    int n = e / INQ, i = e % INQ;
    st_coh(Wt + (size_t)i * NP + n, Win[e]);
  }
  // prefetch step-0 tr (zeros) + img into persistent LDS
  if (blk < 169) {
    #pragma unroll
    for (int q = 0; q < 16; ++q) {
      int br = q * 16 + p2w * 4 + (p2l >> 4);
      gl_lds16(trA + (size_t)br * INQ + icol, &stg_tr[(q * 16 + p2w * 4) * 64]);
      gl_lds16(img + (size_t)br * INQ + icol, &stg_im[(q * 16 + p2w * 4) * 64]);
    }
  }
  ++bt; gbar(barf, bt, blk);

  for (int t = 0; t < T_STEPS; ++t) {
    float* trC = (t & 1) ? trB : trA;   // pre_traces[t]
    float* trN = (t & 1) ? trA : trB;   // pre_traces[t+1] global dst

    // ================= phase 1: block b = batch row =================
    {
      const int b = blk;
      const float* imrow = img + ((size_t)t * BATCH + b) * INQ;
      float* trCrow = trC + (size_t)b * INQ;
      float* trNrow = trN + (size_t)b * INQ;
      if (tid >= 64) {
        // waves 1-3: trace recurrence; trC read is plain cached (own row,
        // fresh since end-of-step fence), write-through for consumers
        for (int i = tid - 64; i < INQ; i += NTHR - 64)
          st_coh(trNrow + i, fmaf(0.9f, trCrow[i], imrow[i]));
      } else {
        // wave 0: any-spike gather (sc1, overlaps compaction), then ordered
        // active-index compaction, padded to multiple of 16
        unsigned long long ax = 0ull, ay = 0ull;
        if (t > 0) {
          const unsigned long long* ap =
              (const unsigned long long*)(anyspk + ((t - 1) & 1) * 256) +
              (tid << 1);
          ax = ld_cohu64(ap);
          ay = ld_cohu64(ap + 1);
        }
        int base = 0;
        for (int c = 0; c < INQ; c += 64) {
          int i = c + tid;
          bool act = (i < INQ) && (imrow[i] != 0.0f);
          unsigned long long m = __ballot(act);
          if (act) s_list[base + (int)__popcll(m & ((1ull << tid) - 1ull))] = i;
          base += (int)__popcll(m);
        }
        int anyv = __any((ax | ay) != 0ull);
        if (tid == 0) {
          int cr = (base + 15) & ~15;
          for (int j = base; j < cr; ++j) s_list[j] = 784;  // zero pad row
          s_cnt = cr;
          s_any = anyv;
        }
      }
      __syncthreads();
      const int cnt = s_cnt;            // multiple of 16
      const int anyPrev = (t > 0) ? s_any : 0;
      const int wPrev = win[b];
      int localmin = 0x7fffffff;

      if (tid < 200) {
        const int n0 = tid * 2;
        const size_t sidx = (size_t)b * NP + n0;
        // sppo post-trace loads: plain cached (own row, fenced), hoisted
        float* sprow = sppo + (size_t)b * 2 * NP + 2 * n0;
        float2 spA = *(const float2*)(sprow);
        float2 spB = *(const float2*)(sprow + 2);
        float2 sv = *(float2*)(syn + sidx);
        if (anyPrev) {
          if (n0     != wPrev) sv.x -= 0.1f;
          if (n0 + 1 != wPrev) sv.y -= 0.1f;
        }
        float c0 = 0.f, c1 = 0.f;
        for (int j = 0; j < cnt; j += 16) {  // 16 cached loads in flight
          float2 wv[16];
          #pragma unroll
          for (int u = 0; u < 16; ++u)
            wv[u] = *(const float2*)(Wt + (size_t)s_list[j + u] * NP + n0);
          #pragma unroll
          for (int u = 0; u < 16; ++u) { c0 += wv[u].x; c1 += wv[u].y; }
        }
        float2 mv = *(float2*)(mem + sidx);
        float syn0 = fmaf(0.9f, sv.x, c0);
        float syn1 = fmaf(0.9f, sv.y, c1);
        float r0 = (mv.x > 1.0f) ? 1.0f : 0.0f;
        float r1 = (mv.y > 1.0f) ? 1.0f : 0.0f;
        float m0 = fmaf(0.8f, mv.x, syn0) - r0;
        float m1 = fmaf(0.8f, mv.y, syn1) - r1;
        float s0 = (m0 > 1.0f) ? 1.0f : 0.0f;
        float s1 = (m1 > 1.0f) ? 1.0f : 0.0f;
        *(float2*)(syn + sidx) = make_float2(syn0, syn1);
        *(float2*)(mem + sidx) = make_float2(m0, m1);
        float p0 = fmaf(0.9f, spA.y, s0);
        float p1 = fmaf(0.9f, spB.y, s1);
        st_coh2(sprow,     make_float2(s0, p0));
        st_coh2(sprow + 2, make_float2(s1, p1));
        const size_t ridx = (size_t)t * BATCH * NOUT + (size_t)b * NOUT + n0;
        *(float2*)(mem_rec + ridx) = make_float2(m0, m1);
        *(float2*)(spk_rec + ridx) = make_float2(s0, s1);
        if      (s0 != 0.f) localmin = n0;
        else if (s1 != 0.f) localmin = n0 + 1;
      }
      // ballot winner reduction (lanes map to ascending neuron index)
      unsigned long long mm = __ballot(localmin != 0x7fffffff);
      int wmin = 0x7fffffff;
      if (mm) {
        int src = __ffsll(mm) - 1;
        wmin = __shfl(localmin, src);
      }
      if ((tid & 63) == 0) s_red[tid >> 6] = wmin;
      __syncthreads();
      if (tid == 0) {
        int w4 = min(min(s_red[0], s_red[1]), min(s_red[2], s_red[3]));
        win[b] = (w4 == 0x7fffffff) ? 0 : w4;
        st_cohu(anyspk + (t & 1) * 256 + blk,
                (w4 != 0x7fffffff) ? 1u : 0u);
      }
    }
    ++bt; gbar(barf, bt, blk);

    // ================= phase 2: STDP weight update =================
    // tr/img resident in LDS; stage sppo via cached gl_lds (fence makes it
    // fresh). Inner loop: raw spk/post, 1e-3 folded into the epilogue
    // (matches ref's scale-after-sum).
    if (blk < 169) {
      const int ib = ib0 + (tid >> 4) * 4;
      const int nb = nb0 + (tid & 15) * 2;
      const bool active = (ib < INQ) && (nb < NOUT);
      const int loff = (tid >> 4) * 4;
      const int soff = (tid & 15) * 4;

      float a00=0,a01=0,a10=0,a11=0,a20=0,a21=0,a30=0,a31=0;

      #define SPSTG(c, buf) {                                                  \
        int b0_ = (c) * 32;                                                    \
        for (int q = 0; q < 2; ++q) {                                          \
          int br = b0_ + q * 16 + p2w * 4 + (p2l >> 4);                        \
          gl_lds16(sppo + (size_t)br * 1024 + scol,                            \
                   &stg_sp[buf][(q * 16 + p2w * 4) * 64]);                     \
        }                                                                      \
      }

      SPSTG(0, 0);
      for (int c = 0; c < 8; ++c) {
        const int buf = c & 1;
        if (c < 7) {
          SPSTG(c + 1, buf ^ 1);
          __builtin_amdgcn_s_waitcnt(0x0F72);     // vmcnt(2): chunk c landed
        } else {
          __builtin_amdgcn_s_waitcnt(0x0F70);     // vmcnt(0)
        }
        __builtin_amdgcn_s_barrier();
        if (active) {
          const float* Ltr = &stg_tr[c * 2048 + loff];
          const float* Lim = &stg_im[c * 2048 + loff];
          const float* Lsp = &stg_sp[buf][soff];
          #pragma unroll 4
          for (int bb = 0; bb < 32; ++bb) {       // b ascending: exact order
            float4 t4 = *(const float4*)(Ltr + bb * 64);
            float4 g4 = *(const float4*)(Lim + bb * 64);
            float4 sp = *(const float4*)(Lsp + bb * 64);
            a00 = fmaf(t4.x, sp.x, fmaf(g4.x, -sp.y, a00));
            a01 = fmaf(t4.x, sp.z, fmaf(g4.x, -sp.w, a01));
            a10 = fmaf(t4.y, sp.x, fmaf(g4.y, -sp.y, a10));
            a11 = fmaf(t4.y, sp.z, fmaf(g4.y, -sp.w, a11));
            a20 = fmaf(t4.z, sp.x, fmaf(g4.z, -sp.y, a20));
            a21 = fmaf(t4.z, sp.z, fmaf(g4.z, -sp.w, a21));
            a30 = fmaf(t4.w, sp.x, fmaf(g4.w, -sp.y, a30));
            a31 = fmaf(t4.w, sp.z, fmaf(g4.w, -sp.w, a31));
          }
        }
        __builtin_amdgcn_s_waitcnt(0xC07F);       // lgkmcnt(0) only
        __builtin_amdgcn_s_barrier();
      }
      #undef SPSTG

      // Wt RMW loads (plain cached; own tile, fresh since mid-step fence),
      // then next-step prefetch streams in the epilogue shadow.
      float2 wl0, wl1, wl2, wl3;
      if (active) {
        wl0 = *(const float2*)(Wt + (size_t)(ib + 0) * NP + nb);
        wl1 = *(const float2*)(Wt + (size_t)(ib + 1) * NP + nb);
        wl2 = *(const float2*)(Wt + (size_t)(ib + 2) * NP + nb);
        wl3 = *(const float2*)(Wt + (size_t)(ib + 3) * NP + nb);
      }
      if (t + 1 < T_STEPS) {
        const float* imn = img + (size_t)(t + 1) * BATCH * INQ;
        #pragma unroll
        for (int q = 0; q < 16; ++q) {
          int br = q * 16 + p2w * 4 + (p2l >> 4);
          gl_lds16(trN + (size_t)br * INQ + icol,
                   &stg_tr[(q * 16 + p2w * 4) * 64]);
          gl_lds16(imn + (size_t)br * INQ + icol,
                   &stg_im[(q * 16 + p2w * 4) * 64]);
        }
      }
      if (active) {
        float2 wv;
        wv = wl0;
        wv.x = fminf(fmaxf(wv.x + 1e-3f * a00, 0.f), 1.f);
        wv.y = fminf(fmaxf(wv.y + 1e-3f * a01, 0.f), 1.f);
        st_coh2(Wt + (size_t)(ib + 0) * NP + nb, wv);
        wv = wl1;
        wv.x = fminf(fmaxf(wv.x + 1e-3f * a10, 0.f), 1.f);
        wv.y = fminf(fmaxf(wv.y + 1e-3f * a11, 0.f), 1.f);
        st_coh2(Wt + (size_t)(ib + 1) * NP + nb, wv);
        wv = wl2;
        wv.x = fminf(fmaxf(wv.x + 1e-3f * a20, 0.f), 1.f);
        wv.y = fminf(fmaxf(wv.y + 1e-3f * a21, 0.f), 1.f);
        st_coh2(Wt + (size_t)(ib + 2) * NP + nb, wv);
        wv = wl3;
        wv.x = fminf(fmaxf(wv.x + 1e-3f * a30, 0.f), 1.f);
        wv.y = fminf(fmaxf(wv.y + 1e-3f * a31, 0.f), 1.f);
        st_coh2(Wt + (size_t)(ib + 3) * NP + nb, wv);
      }
    }
    ++bt; gbar(barf, bt, blk);
  }

  // ---- final: W_out[n][i] = Wt[i][n] (plain; fenced at last gbar) ----
  for (int e = blk * NTHR + tid; e < NOUT * INQ; e += GRID * NTHR) {
    int n = e / INQ, i = e % INQ;
    Wout[e] = Wt[(size_t)i * NP + n];
  }
}

extern "C" void kernel_launch(void* const* d_in, const int* in_sizes, int n_in,
                              void* d_out, int out_size, void* d_ws, size_t ws_size,
                              hipStream_t stream) {
  const float* img = (const float*)d_in[0];
  const float* W   = (const float*)d_in[1];
  float* out = (float*)d_out;
  float* ws  = (float*)d_ws;

  hipMemsetAsync(d_ws, 0, (size_t)WS_FLOATS * sizeof(float), stream);

  void* args[] = { (void*)&img, (void*)&W, (void*)&out, (void*)&ws };
  hipError_t rc = hipLaunchCooperativeKernel((const void*)snn_kernel,
                                             dim3(GRID), dim3(NTHR),
                                             args, 0, stream);
  if (rc != hipSuccess) {
    // Hand-rolled grid barrier; 151 KB LDS -> 1 block/CU, grid == #CUs:
    // co-residency holds by construction under a plain launch.
    hipLaunchKernelGGL(snn_kernel, dim3(GRID), dim3(NTHR), 0, stream,
                       img, W, out, ws);
  }
}

// Round 8
// 7429.528 us; speedup vs baseline: 1.3635x; 1.3635x over previous
//
#include <hip/hip_runtime.h>

// SNN-MNIST forward + STDP, MI355X persistent cooperative kernel.
// Round 12: r5 base (7410 us, passing) + lambda-robust pipeline depth:
//  (1) gather rounds 3->2: active list padded to 32, wv[32]
//  (2) sppo chunk pipeline 2->3-deep (vmcnt(4)/2/0), sched_barrier belts
//  (3) Wt RMW tile loads hoisted to phase-2 entry (oldest in vm queue;
//      ledger: entry = 4 wl + 6 stage, iter0 vmcnt(4) retires wl*4+chunk0*2)
//  (4) keep r11's verified 1e-3 epilogue fold (absmax 2.0 unchanged)
// r11's plain-load + buffer_inv REVERTED (FETCH invariant, dur +13.7us/step
// -> theory falsified). Belts kept: __launch_bounds__(256,2), coop rc check.

#define T_STEPS 200
#define BATCH   256
#define INQ     784
#define NOUT    400
#define NP      512
#define GRID    256
#define NTHR    256

// ws layout (float offsets)
#define OFF_WT    0            // Wt [785][512] (row 784 = zero pad for gather)
#define OFF_SYN   401920       // syn [256][512]         (block-private)
#define OFF_MEM   532992       // mem [256][512]         (block-private)
#define OFF_SPPO  664064       // interleaved (spk,post): [256][1024]  (sc1)
#define OFF_TRA   926208       // trA [256][784]         (sc1)
#define OFF_TRB   1126912      // trB [256][784]         (sc1)
#define OFF_WIN   1327616      // int win[256]           (block-private)
#define OFF_ANY   1327872      // u32 anyspk[2][256]     (sc1, ping-pong)
#define OFF_BARF  1328384      // u32 barf[256]: all-to-all barrier flags
#define WS_FLOATS 1332224

// ---- agent-coherent (sc1) access helpers ----
__device__ __forceinline__ float ld_coh(const float* p) {
  return __hip_atomic_load(p, __ATOMIC_RELAXED, __HIP_MEMORY_SCOPE_AGENT);
}
__device__ __forceinline__ float2 ld_coh2(const float* p) {
  union { unsigned long long u; float2 f; } c;
  c.u = __hip_atomic_load((const unsigned long long*)p, __ATOMIC_RELAXED,
                          __HIP_MEMORY_SCOPE_AGENT);
  return c.f;
}
__device__ __forceinline__ void st_coh(float* p, float v) {
  __hip_atomic_store(p, v, __ATOMIC_RELAXED, __HIP_MEMORY_SCOPE_AGENT);
}
__device__ __forceinline__ void st_coh2(float* p, float2 v) {
  union { unsigned long long u; float2 f; } c; c.f = v;
  __hip_atomic_store((unsigned long long*)p, c.u, __ATOMIC_RELAXED,
                     __HIP_MEMORY_SCOPE_AGENT);
}
__device__ __forceinline__ void st_cohu(unsigned* p, unsigned v) {
  __hip_atomic_store(p, v, __ATOMIC_RELAXED, __HIP_MEMORY_SCOPE_AGENT);
}
__device__ __forceinline__ unsigned long long ld_cohu64(const unsigned long long* p) {
  return __hip_atomic_load(p, __ATOMIC_RELAXED, __HIP_MEMORY_SCOPE_AGENT);
}

__device__ __forceinline__ void gl_lds16(const float* g, float* l) {       // cached
  __builtin_amdgcn_global_load_lds(
      (const __attribute__((address_space(1))) void*)g,
      (__attribute__((address_space(3))) void*)l, 16, 0, 0);
}
__device__ __forceinline__ void gl_lds16c(const float* g, float* l) {      // sc1
  __builtin_amdgcn_global_load_lds(
      (const __attribute__((address_space(1))) void*)g,
      (__attribute__((address_space(3))) void*)l, 16, 0, 0x10);
}

// All-to-all flag barrier, k = 1-based ordinal. Arrival: each block STORES
// its own flag (16 lines total, no RMW contention). Release: wave 0 of every
// block polls all 256 flags (2 x 8B loads/lane). __syncthreads() before
// arrival drains vmcnt, making write-through stores globally visible.
__device__ __forceinline__ void gbar(unsigned* barf, unsigned k, int blk) {
  __syncthreads();
  if (threadIdx.x == 0)
    st_cohu(barf + blk, k);
  if (threadIdx.x < 64) {
    const unsigned long long* p =
        (const unsigned long long*)barf + (threadIdx.x << 1);
    for (;;) {
      unsigned long long a = ld_cohu64(p);
      unsigned long long bq = ld_cohu64(p + 1);
      unsigned m0 = (unsigned)a, m1 = (unsigned)(a >> 32);
      unsigned m2 = (unsigned)bq, m3 = (unsigned)(bq >> 32);
      unsigned mn = m0 < m1 ? m0 : m1;
      unsigned mo = m2 < m3 ? m2 : m3;
      mn = mn < mo ? mn : mo;
      if (__all(mn >= k)) break;
      __builtin_amdgcn_s_sleep(1);
    }
  }
  __syncthreads();
}

__global__ void __launch_bounds__(NTHR, 2) snn_kernel(
    const float* __restrict__ img,   // [200][256][784]
    const float* __restrict__ Win,   // [400][784]
    float* __restrict__ out,         // mem_rec | spk_rec | W_final
    float* ws)
{
  float* Wt    = ws + OFF_WT;
  float* syn   = ws + OFF_SYN;
  float* mem   = ws + OFF_MEM;
  float* sppo  = ws + OFF_SPPO;
  float* trA   = ws + OFF_TRA;
  float* trB   = ws + OFF_TRB;
  int*   win   = (int*)(ws + OFF_WIN);
  unsigned* anyspk = (unsigned*)(ws + OFF_ANY);
  unsigned* barf   = (unsigned*)(ws + OFF_BARF);

  float* mem_rec = out;
  float* spk_rec = out + (size_t)T_STEPS * BATCH * NOUT;
  float* Wout    = out + (size_t)2 * T_STEPS * BATCH * NOUT;

  const int tid = threadIdx.x;
  const int blk = blockIdx.x;
  unsigned bt = 0;                    // barrier ordinal

  __shared__ float stg_tr[16384];     // tr  [256][64]  (persistent per step)
  __shared__ float stg_im[16384];     // img [256][64]  (persistent per step)
  __shared__ float stg_sp[3][2048];   // sppo chunk 3-deep pipeline [32][64]
  __shared__ int s_list[816];
  __shared__ int s_cnt, s_any;
  __shared__ int s_red[4];

  // phase-2 tile geometry (also used for prefetch)
  const int p2w = tid >> 6, p2l = tid & 63;
  const int bi = blk / 13, bn = blk % 13;
  const int ib0 = bi * 64, nb0 = bn * 32;
  int icol = ib0 + (p2l & 15) * 4;
  if (icol > INQ - 4) icol = INQ - 4;           // clamp (garbage, unused)
  const int scol = 2 * nb0 + (p2l & 15) * 4;

  // ---- init: Wt[i][n] = Win[n][i], written coherently ----
  for (int e = blk * NTHR + tid; e < NOUT * INQ; e += GRID * NTHR) {
    int n = e / INQ, i = e % INQ;
    st_coh(Wt + (size_t)i * NP + n, Win[e]);
  }
  // prefetch step-0 tr (zeros) + img into persistent LDS
  if (blk < 169) {
    #pragma unroll
    for (int q = 0; q < 16; ++q) {
      int br = q * 16 + p2w * 4 + (p2l >> 4);
      gl_lds16c(trA + (size_t)br * INQ + icol, &stg_tr[(q * 16 + p2w * 4) * 64]);
      gl_lds16 (img + (size_t)br * INQ + icol, &stg_im[(q * 16 + p2w * 4) * 64]);
    }
  }
  ++bt; gbar(barf, bt, blk);

  for (int t = 0; t < T_STEPS; ++t) {
    float* trC = (t & 1) ? trB : trA;   // pre_traces[t]
    float* trN = (t & 1) ? trA : trB;   // pre_traces[t+1] global dst

    // ================= phase 1: block b = batch row =================
    {
      const int b = blk;
      const float* imrow = img + ((size_t)t * BATCH + b) * INQ;
      float* trCrow = trC + (size_t)b * INQ;
      float* trNrow = trN + (size_t)b * INQ;
      if (tid >= 64) {
        // waves 1-3: trace recurrence tr_{t+1} = 0.9*tr_t + img_t
        for (int i = tid - 64; i < INQ; i += NTHR - 64)
          st_coh(trNrow + i, fmaf(0.9f, ld_coh(trCrow + i), imrow[i]));
      } else {
        // wave 0: any-spike gather (overlaps compaction), then ordered
        // active-index compaction, padded to multiple of 32
        unsigned long long ax = 0ull, ay = 0ull;
        if (t > 0) {
          const unsigned long long* ap =
              (const unsigned long long*)(anyspk + ((t - 1) & 1) * 256) +
              (tid << 1);
          ax = ld_cohu64(ap);
          ay = ld_cohu64(ap + 1);
        }
        int base = 0;
        for (int c = 0; c < INQ; c += 64) {
          int i = c + tid;
          bool act = (i < INQ) && (imrow[i] != 0.0f);
          unsigned long long m = __ballot(act);
          if (act) s_list[base + (int)__popcll(m & ((1ull << tid) - 1ull))] = i;
          base += (int)__popcll(m);
        }
        int anyv = __any((ax | ay) != 0ull);
        if (tid == 0) {
          int cr = (base + 31) & ~31;
          for (int j = base; j < cr; ++j) s_list[j] = 784;  // zero pad row
          s_cnt = cr;
          s_any = anyv;
        }
      }
      __syncthreads();
      const int cnt = s_cnt;            // multiple of 32
      const int anyPrev = (t > 0) ? s_any : 0;
      const int wPrev = win[b];
      int localmin = 0x7fffffff;

      if (tid < 200) {
        const int n0 = tid * 2;
        const size_t sidx = (size_t)b * NP + n0;
        // hoist sppo post-trace loads ahead of the gather (independent)
        float* sprow = sppo + (size_t)b * 2 * NP + 2 * n0;
        float2 spA = ld_coh2(sprow);
        float2 spB = ld_coh2(sprow + 2);
        float2 sv = *(float2*)(syn + sidx);
        if (anyPrev) {
          if (n0     != wPrev) sv.x -= 0.1f;
          if (n0 + 1 != wPrev) sv.y -= 0.1f;
        }
        float c0 = 0.f, c1 = 0.f;
        for (int j = 0; j < cnt; j += 32) {  // 32 coherent loads in flight
          float2 wv[32];
          #pragma unroll
          for (int u = 0; u < 32; ++u)
            wv[u] = ld_coh2(Wt + (size_t)s_list[j + u] * NP + n0);
          #pragma unroll
          for (int u = 0; u < 32; ++u) { c0 += wv[u].x; c1 += wv[u].y; }
        }
        float2 mv = *(float2*)(mem + sidx);
        float syn0 = fmaf(0.9f, sv.x, c0);
        float syn1 = fmaf(0.9f, sv.y, c1);
        float r0 = (mv.x > 1.0f) ? 1.0f : 0.0f;
        float r1 = (mv.y > 1.0f) ? 1.0f : 0.0f;
        float m0 = fmaf(0.8f, mv.x, syn0) - r0;
        float m1 = fmaf(0.8f, mv.y, syn1) - r1;
        float s0 = (m0 > 1.0f) ? 1.0f : 0.0f;
        float s1 = (m1 > 1.0f) ? 1.0f : 0.0f;
        *(float2*)(syn + sidx) = make_float2(syn0, syn1);
        *(float2*)(mem + sidx) = make_float2(m0, m1);
        float p0 = fmaf(0.9f, spA.y, s0);
        float p1 = fmaf(0.9f, spB.y, s1);
        st_coh2(sprow,     make_float2(s0, p0));
        st_coh2(sprow + 2, make_float2(s1, p1));
        const size_t ridx = (size_t)t * BATCH * NOUT + (size_t)b * NOUT + n0;
        *(float2*)(mem_rec + ridx) = make_float2(m0, m1);
        *(float2*)(spk_rec + ridx) = make_float2(s0, s1);
        if      (s0 != 0.f) localmin = n0;
        else if (s1 != 0.f) localmin = n0 + 1;
      }
      // ballot winner reduction (lanes map to ascending neuron index)
      unsigned long long mm = __ballot(localmin != 0x7fffffff);
      int wmin = 0x7fffffff;
      if (mm) {
        int src = __ffsll(mm) - 1;
        wmin = __shfl(localmin, src);
      }
      if ((tid & 63) == 0) s_red[tid >> 6] = wmin;
      __syncthreads();
      if (tid == 0) {
        int w4 = min(min(s_red[0], s_red[1]), min(s_red[2], s_red[3]));
        win[b] = (w4 == 0x7fffffff) ? 0 : w4;
        st_cohu(anyspk + (t & 1) * 256 + blk,
                (w4 != 0x7fffffff) ? 1u : 0u);
      }
    }
    ++bt; gbar(barf, bt, blk);

    // ================= phase 2: STDP weight update =================
    // tr/img resident in LDS (prefetched last epilogue). Wt RMW tile loads
    // issued FIRST (oldest in vm queue -> retire before chunk waits), then
    // 3-deep sppo pipeline. Ledger: entry queue = [wl x4][S0 x2][S1 x2]
    // [S2 x2]; iter0 vmcnt(4) retires wl*4 + chunk0*2; iters 1..5 vmcnt(4)
    // retires chunk c; c==6 vmcnt(2); c==7 vmcnt(0). SPSTG(c+3) re-issued
    // only AFTER the lgkmcnt(0)+barrier (its buffer (c+3)%3==c%3 is the one
    // all waves just finished reading).
    if (blk < 169) {
      const int ib = ib0 + (tid >> 4) * 4;
      const int nb = nb0 + (tid & 15) * 2;
      const bool active = (ib < INQ) && (nb < NOUT);
      const int loff = (tid >> 4) * 4;
      const int soff = (tid & 15) * 4;

      float2 wl0, wl1, wl2, wl3;
      if (active) {
        wl0 = ld_coh2(Wt + (size_t)(ib + 0) * NP + nb);
        wl1 = ld_coh2(Wt + (size_t)(ib + 1) * NP + nb);
        wl2 = ld_coh2(Wt + (size_t)(ib + 2) * NP + nb);
        wl3 = ld_coh2(Wt + (size_t)(ib + 3) * NP + nb);
      }

      float a00=0,a01=0,a10=0,a11=0,a20=0,a21=0,a30=0,a31=0;

      #define SPSTG(c_, buf_) {                                                \
        int b0_ = (c_) * 32;                                                   \
        for (int q = 0; q < 2; ++q) {                                          \
          int br = b0_ + q * 16 + p2w * 4 + (p2l >> 4);                        \
          gl_lds16c(sppo + (size_t)br * 1024 + scol,                           \
                    &stg_sp[buf_][(q * 16 + p2w * 4) * 64]);                   \
        }                                                                      \
      }

      SPSTG(0, 0); SPSTG(1, 1); SPSTG(2, 2);
      for (int c = 0; c < 8; ++c) {
        if (c < 6)       __builtin_amdgcn_s_waitcnt(0x0F74);  // vmcnt(4)
        else if (c == 6) __builtin_amdgcn_s_waitcnt(0x0F72);  // vmcnt(2)
        else             __builtin_amdgcn_s_waitcnt(0x0F70);  // vmcnt(0)
        __builtin_amdgcn_sched_barrier(0);
        __builtin_amdgcn_s_barrier();
        if (active) {
          const float* Ltr = &stg_tr[c * 2048 + loff];
          const float* Lim = &stg_im[c * 2048 + loff];
          const float* Lsp = &stg_sp[c % 3][soff];
          #pragma unroll 4
          for (int bb = 0; bb < 32; ++bb) {       // b ascending: exact order
            float4 t4 = *(const float4*)(Ltr + bb * 64);
            float4 g4 = *(const float4*)(Lim + bb * 64);
            float4 sp = *(const float4*)(Lsp + bb * 64);
            a00 = fmaf(t4.x, sp.x, fmaf(g4.x, -sp.y, a00));
            a01 = fmaf(t4.x, sp.z, fmaf(g4.x, -sp.w, a01));
            a10 = fmaf(t4.y, sp.x, fmaf(g4.y, -sp.y, a10));
            a11 = fmaf(t4.y, sp.z, fmaf(g4.y, -sp.w, a11));
            a20 = fmaf(t4.z, sp.x, fmaf(g4.z, -sp.y, a20));
            a21 = fmaf(t4.z, sp.z, fmaf(g4.z, -sp.w, a21));
            a30 = fmaf(t4.w, sp.x, fmaf(g4.w, -sp.y, a30));
            a31 = fmaf(t4.w, sp.z, fmaf(g4.w, -sp.w, a31));
          }
        }
        __builtin_amdgcn_s_waitcnt(0xC07F);       // lgkmcnt(0) only
        __builtin_amdgcn_sched_barrier(0);
        __builtin_amdgcn_s_barrier();
        if (c < 5) SPSTG(c + 3, (c + 3) % 3);
      }
      #undef SPSTG

      // next-step tr/img prefetch streams in the epilogue + barrier shadow
      if (t + 1 < T_STEPS) {
        const float* imn = img + (size_t)(t + 1) * BATCH * INQ;
        #pragma unroll
        for (int q = 0; q < 16; ++q) {
          int br = q * 16 + p2w * 4 + (p2l >> 4);
          gl_lds16c(trN + (size_t)br * INQ + icol,
                    &stg_tr[(q * 16 + p2w * 4) * 64]);
          gl_lds16 (imn + (size_t)br * INQ + icol,
                    &stg_im[(q * 16 + p2w * 4) * 64]);
        }
      }
      if (active) {
        float2 wv;
        wv = wl0;
        wv.x = fminf(fmaxf(wv.x + 1e-3f * a00, 0.f), 1.f);
        wv.y = fminf(fmaxf(wv.y + 1e-3f * a01, 0.f), 1.f);
        st_coh2(Wt + (size_t)(ib + 0) * NP + nb, wv);
        wv = wl1;
        wv.x = fminf(fmaxf(wv.x + 1e-3f * a10, 0.f), 1.f);
        wv.y = fminf(fmaxf(wv.y + 1e-3f * a11, 0.f), 1.f);
        st_coh2(Wt + (size_t)(ib + 1) * NP + nb, wv);
        wv = wl2;
        wv.x = fminf(fmaxf(wv.x + 1e-3f * a20, 0.f), 1.f);
        wv.y = fminf(fmaxf(wv.y + 1e-3f * a21, 0.f), 1.f);
        st_coh2(Wt + (size_t)(ib + 2) * NP + nb, wv);
        wv = wl3;
        wv.x = fminf(fmaxf(wv.x + 1e-3f * a30, 0.f), 1.f);
        wv.y = fminf(fmaxf(wv.y + 1e-3f * a31, 0.f), 1.f);
        st_coh2(Wt + (size_t)(ib + 3) * NP + nb, wv);
      }
    }
    ++bt; gbar(barf, bt, blk);
  }

  // ---- final: W_out[n][i] = Wt[i][n] ----
  for (int e = blk * NTHR + tid; e < NOUT * INQ; e += GRID * NTHR) {
    int n = e / INQ, i = e % INQ;
    Wout[e] = ld_coh(Wt + (size_t)i * NP + n);
  }
}

extern "C" void kernel_launch(void* const* d_in, const int* in_sizes, int n_in,
                              void* d_out, int out_size, void* d_ws, size_t ws_size,
                              hipStream_t stream) {
  const float* img = (const float*)d_in[0];
  const float* W   = (const float*)d_in[1];
  float* out = (float*)d_out;
  float* ws  = (float*)d_ws;

  hipMemsetAsync(d_ws, 0, (size_t)WS_FLOATS * sizeof(float), stream);

  void* args[] = { (void*)&img, (void*)&W, (void*)&out, (void*)&ws };
  hipError_t rc = hipLaunchCooperativeKernel((const void*)snn_kernel,
                                             dim3(GRID), dim3(NTHR),
                                             args, 0, stream);
  if (rc != hipSuccess) {
    // Hand-rolled grid barrier; ~155 KB LDS -> 1 block/CU, grid == #CUs:
    // co-residency holds by construction under a plain launch.
    hipLaunchKernelGGL(snn_kernel, dim3(GRID), dim3(NTHR), 0, stream,
                       img, W, out, ws);
  }
}

// Round 9
// 6837.144 us; speedup vs baseline: 1.4816x; 1.0866x over previous
//
#include <hip/hip_runtime.h>

// SNN-MNIST forward + STDP, MI355X persistent cooperative kernel.
// Round 13: single axis = wave-level parallelism. NTHR 256->512 (8 waves/CU,
// 2/SIMD, Occupancy 12.4->24.9%). Rationale: r5/r12 proved barrier & pipeline
// lambda-shaving moves <=3%; counters show 1 wave/SIMD, so ALL intra-phase
// latency is exposed (no TLP). Doubling resident waves halves exposed stall
// if that theory is right. Mappings rescaled, arithmetic order per output
// scalar identical to r12:
//  - phase 1: 1 neuron/thread (tid<400), scalar gather 32-deep, 448-thread
//    trace recurrence, 8-wave ballot reduce
//  - phase 2: 2i x 2n per thread, float2 LDS reads, 1 sppo stage load per
//    thread per chunk (3-deep: vmcnt 2,2,2,2,2,2,1,0; wl/no-wl waves agree)
// Belts: __launch_bounds__(512,2), coop rc-check fallback, sched_barrier
// after raw waitcnts.

#define T_STEPS 200
#define BATCH   256
#define INQ     784
#define NOUT    400
#define NP      512
#define GRID    256
#define NTHR    512

// ws layout (float offsets)
#define OFF_WT    0            // Wt [785][512] (row 784 = zero pad for gather)
#define OFF_SYN   401920       // syn [256][512]         (block-private)
#define OFF_MEM   532992       // mem [256][512]         (block-private)
#define OFF_SPPO  664064       // interleaved (spk,post): [256][1024]  (sc1)
#define OFF_TRA   926208       // trA [256][784]         (sc1)
#define OFF_TRB   1126912      // trB [256][784]         (sc1)
#define OFF_WIN   1327616      // int win[256]           (block-private)
#define OFF_ANY   1327872      // u32 anyspk[2][256]     (sc1, ping-pong)
#define OFF_BARF  1328384      // u32 barf[256]: all-to-all barrier flags
#define WS_FLOATS 1332224

// ---- agent-coherent (sc1) access helpers ----
__device__ __forceinline__ float ld_coh(const float* p) {
  return __hip_atomic_load(p, __ATOMIC_RELAXED, __HIP_MEMORY_SCOPE_AGENT);
}
__device__ __forceinline__ float2 ld_coh2(const float* p) {
  union { unsigned long long u; float2 f; } c;
  c.u = __hip_atomic_load((const unsigned long long*)p, __ATOMIC_RELAXED,
                          __HIP_MEMORY_SCOPE_AGENT);
  return c.f;
}
__device__ __forceinline__ void st_coh(float* p, float v) {
  __hip_atomic_store(p, v, __ATOMIC_RELAXED, __HIP_MEMORY_SCOPE_AGENT);
}
__device__ __forceinline__ void st_coh2(float* p, float2 v) {
  union { unsigned long long u; float2 f; } c; c.f = v;
  __hip_atomic_store((unsigned long long*)p, c.u, __ATOMIC_RELAXED,
                     __HIP_MEMORY_SCOPE_AGENT);
}
__device__ __forceinline__ void st_cohu(unsigned* p, unsigned v) {
  __hip_atomic_store(p, v, __ATOMIC_RELAXED, __HIP_MEMORY_SCOPE_AGENT);
}
__device__ __forceinline__ unsigned long long ld_cohu64(const unsigned long long* p) {
  return __hip_atomic_load(p, __ATOMIC_RELAXED, __HIP_MEMORY_SCOPE_AGENT);
}

__device__ __forceinline__ void gl_lds16(const float* g, float* l) {       // cached
  __builtin_amdgcn_global_load_lds(
      (const __attribute__((address_space(1))) void*)g,
      (__attribute__((address_space(3))) void*)l, 16, 0, 0);
}
__device__ __forceinline__ void gl_lds16c(const float* g, float* l) {      // sc1
  __builtin_amdgcn_global_load_lds(
      (const __attribute__((address_space(1))) void*)g,
      (__attribute__((address_space(3))) void*)l, 16, 0, 0x10);
}

// All-to-all flag barrier, k = 1-based ordinal. Arrival: each block STORES
// its own flag. Release: wave 0 polls all 256 flags (2 x 8B loads/lane).
// __syncthreads() before arrival drains vmcnt (write-through visible).
__device__ __forceinline__ void gbar(unsigned* barf, unsigned k, int blk) {
  __syncthreads();
  if (threadIdx.x == 0)
    st_cohu(barf + blk, k);
  if (threadIdx.x < 64) {
    const unsigned long long* p =
        (const unsigned long long*)barf + (threadIdx.x << 1);
    for (;;) {
      unsigned long long a = ld_cohu64(p);
      unsigned long long bq = ld_cohu64(p + 1);
      unsigned m0 = (unsigned)a, m1 = (unsigned)(a >> 32);
      unsigned m2 = (unsigned)bq, m3 = (unsigned)(bq >> 32);
      unsigned mn = m0 < m1 ? m0 : m1;
      unsigned mo = m2 < m3 ? m2 : m3;
      mn = mn < mo ? mn : mo;
      if (__all(mn >= k)) break;
      __builtin_amdgcn_s_sleep(1);
    }
  }
  __syncthreads();
}

__global__ void __launch_bounds__(NTHR, 2) snn_kernel(
    const float* __restrict__ img,   // [200][256][784]
    const float* __restrict__ Win,   // [400][784]
    float* __restrict__ out,         // mem_rec | spk_rec | W_final
    float* ws)
{
  float* Wt    = ws + OFF_WT;
  float* syn   = ws + OFF_SYN;
  float* mem   = ws + OFF_MEM;
  float* sppo  = ws + OFF_SPPO;
  float* trA   = ws + OFF_TRA;
  float* trB   = ws + OFF_TRB;
  int*   win   = (int*)(ws + OFF_WIN);
  unsigned* anyspk = (unsigned*)(ws + OFF_ANY);
  unsigned* barf   = (unsigned*)(ws + OFF_BARF);

  float* mem_rec = out;
  float* spk_rec = out + (size_t)T_STEPS * BATCH * NOUT;
  float* Wout    = out + (size_t)2 * T_STEPS * BATCH * NOUT;

  const int tid = threadIdx.x;
  const int blk = blockIdx.x;
  unsigned bt = 0;                    // barrier ordinal

  __shared__ float stg_tr[16384];     // tr  [256][64]  (persistent per step)
  __shared__ float stg_im[16384];     // img [256][64]  (persistent per step)
  __shared__ float stg_sp[3][2048];   // sppo chunk 3-deep pipeline [32][64]
  __shared__ int s_list[816];
  __shared__ int s_cnt, s_any;
  __shared__ int s_red[8];

  // phase-2 tile geometry (also used for prefetch); 8 waves
  const int p2w = tid >> 6, p2l = tid & 63;
  const int bi = blk / 13, bn = blk % 13;
  const int ib0 = bi * 64, nb0 = bn * 32;
  int icol = ib0 + (p2l & 15) * 4;
  if (icol > INQ - 4) icol = INQ - 4;           // clamp (garbage, unused)
  const int scol = 2 * nb0 + (p2l & 15) * 4;

  // ---- init: Wt[i][n] = Win[n][i], written coherently ----
  for (int e = blk * NTHR + tid; e < NOUT * INQ; e += GRID * NTHR) {
    int n = e / INQ, i = e % INQ;
    st_coh(Wt + (size_t)i * NP + n, Win[e]);
  }
  // prefetch step-0 tr (zeros) + img into persistent LDS (8 passes x 32 rows)
  if (blk < 169) {
    #pragma unroll
    for (int q = 0; q < 8; ++q) {
      int br = q * 32 + p2w * 4 + (p2l >> 4);
      gl_lds16c(trA + (size_t)br * INQ + icol, &stg_tr[(q * 32 + p2w * 4) * 64]);
      gl_lds16 (img + (size_t)br * INQ + icol, &stg_im[(q * 32 + p2w * 4) * 64]);
    }
  }
  ++bt; gbar(barf, bt, blk);

  for (int t = 0; t < T_STEPS; ++t) {
    float* trC = (t & 1) ? trB : trA;   // pre_traces[t]
    float* trN = (t & 1) ? trA : trB;   // pre_traces[t+1] global dst

    // ================= phase 1: block b = batch row =================
    {
      const int b = blk;
      const float* imrow = img + ((size_t)t * BATCH + b) * INQ;
      float* trCrow = trC + (size_t)b * INQ;
      float* trNrow = trN + (size_t)b * INQ;
      if (tid >= 64) {
        // waves 1-7: trace recurrence tr_{t+1} = 0.9*tr_t + img_t
        for (int i = tid - 64; i < INQ; i += NTHR - 64)
          st_coh(trNrow + i, fmaf(0.9f, ld_coh(trCrow + i), imrow[i]));
      } else {
        // wave 0: any-spike gather (overlaps compaction), then ordered
        // active-index compaction, padded to multiple of 32
        unsigned long long ax = 0ull, ay = 0ull;
        if (t > 0) {
          const unsigned long long* ap =
              (const unsigned long long*)(anyspk + ((t - 1) & 1) * 256) +
              (tid << 1);
          ax = ld_cohu64(ap);
          ay = ld_cohu64(ap + 1);
        }
        int base = 0;
        for (int c = 0; c < INQ; c += 64) {
          int i = c + tid;
          bool act = (i < INQ) && (imrow[i] != 0.0f);
          unsigned long long m = __ballot(act);
          if (act) s_list[base + (int)__popcll(m & ((1ull << tid) - 1ull))] = i;
          base += (int)__popcll(m);
        }
        int anyv = __any((ax | ay) != 0ull);
        if (tid == 0) {
          int cr = (base + 31) & ~31;
          for (int j = base; j < cr; ++j) s_list[j] = 784;  // zero pad row
          s_cnt = cr;
          s_any = anyv;
        }
      }
      __syncthreads();
      const int cnt = s_cnt;            // multiple of 32
      const int anyPrev = (t > 0) ? s_any : 0;
      const int wPrev = win[b];
      int localmin = 0x7fffffff;

      if (tid < NOUT) {
        const int n0 = tid;             // one neuron per thread
        const size_t sidx = (size_t)b * NP + n0;
        // hoist sppo post-trace load ahead of the gather (independent)
        float* sprow = sppo + (size_t)b * 2 * NP + 2 * n0;
        float2 sp2 = ld_coh2(sprow);    // (spk, post)
        float sv = syn[sidx];
        if (anyPrev && n0 != wPrev) sv -= 0.1f;
        float c0 = 0.f;
        for (int j = 0; j < cnt; j += 32) {  // 32 coherent loads in flight
          float wv[32];
          #pragma unroll
          for (int u = 0; u < 32; ++u)
            wv[u] = ld_coh(Wt + (size_t)s_list[j + u] * NP + n0);
          #pragma unroll
          for (int u = 0; u < 32; ++u) c0 += wv[u];
        }
        float mv = mem[sidx];
        float syn0 = fmaf(0.9f, sv, c0);
        float r0 = (mv > 1.0f) ? 1.0f : 0.0f;
        float m0 = fmaf(0.8f, mv, syn0) - r0;
        float s0 = (m0 > 1.0f) ? 1.0f : 0.0f;
        syn[sidx] = syn0;
        mem[sidx] = m0;
        float p0 = fmaf(0.9f, sp2.y, s0);
        st_coh2(sprow, make_float2(s0, p0));
        const size_t ridx = (size_t)t * BATCH * NOUT + (size_t)b * NOUT + n0;
        mem_rec[ridx] = m0;
        spk_rec[ridx] = s0;
        if (s0 != 0.f) localmin = n0;
      }
      // ballot winner reduction (lanes map to ascending neuron index)
      unsigned long long mm = __ballot(localmin != 0x7fffffff);
      int wmin = 0x7fffffff;
      if (mm) {
        int src = __ffsll(mm) - 1;
        wmin = __shfl(localmin, src);
      }
      if ((tid & 63) == 0) s_red[tid >> 6] = wmin;
      __syncthreads();
      if (tid == 0) {
        int w4 = min(min(min(s_red[0], s_red[1]), min(s_red[2], s_red[3])),
                     min(min(s_red[4], s_red[5]), min(s_red[6], s_red[7])));
        win[b] = (w4 == 0x7fffffff) ? 0 : w4;
        st_cohu(anyspk + (t & 1) * 256 + blk,
                (w4 != 0x7fffffff) ? 1u : 0u);
      }
    }
    ++bt; gbar(barf, bt, blk);

    // ================= phase 2: STDP weight update =================
    // tr/img resident in LDS. Wt RMW loads issued FIRST (oldest in queue).
    // 3-deep sppo pipeline, 1 load/thread/chunk. Ledger (per wave):
    //  wl-wave entry: [wl0,wl1,S0,S1,S2]; no-wl wave: [S0,S1,S2].
    //  c=0..5: vmcnt(2) -> chunk c landed (both cases); c=6: vmcnt(1);
    //  c=7: vmcnt(0). SPSTG(c+3) re-issued AFTER the consume barrier.
    if (blk < 169) {
      const int ib = ib0 + (tid >> 4) * 2;     // 2 i-rows per thread
      const int nb = nb0 + (tid & 15) * 2;     // 2 n-cols per thread
      const bool active = (ib < INQ) && (nb < NOUT);
      const int loff = (tid >> 4) * 2;
      const int soff = (tid & 15) * 4;

      float2 wl0, wl1;
      if (active) {
        wl0 = ld_coh2(Wt + (size_t)(ib + 0) * NP + nb);
        wl1 = ld_coh2(Wt + (size_t)(ib + 1) * NP + nb);
      }

      float a00 = 0, a01 = 0, a10 = 0, a11 = 0;

      #define SPSTG(c_, buf_) {                                                \
        int br = (c_) * 32 + p2w * 4 + (p2l >> 4);                             \
        gl_lds16c(sppo + (size_t)br * 1024 + scol,                             \
                  &stg_sp[buf_][(p2w * 4) * 64]);                              \
      }

      SPSTG(0, 0); SPSTG(1, 1); SPSTG(2, 2);
      for (int c = 0; c < 8; ++c) {
        if (c < 6)       __builtin_amdgcn_s_waitcnt(0x0F72);  // vmcnt(2)
        else if (c == 6) __builtin_amdgcn_s_waitcnt(0x0F71);  // vmcnt(1)
        else             __builtin_amdgcn_s_waitcnt(0x0F70);  // vmcnt(0)
        __builtin_amdgcn_sched_barrier(0);
        __builtin_amdgcn_s_barrier();
        if (active) {
          const float* Ltr = &stg_tr[c * 2048 + loff];
          const float* Lim = &stg_im[c * 2048 + loff];
          const float* Lsp = &stg_sp[c % 3][soff];
          #pragma unroll 4
          for (int bb = 0; bb < 32; ++bb) {       // b ascending: exact order
            float2 t2 = *(const float2*)(Ltr + bb * 64);
            float2 g2 = *(const float2*)(Lim + bb * 64);
            float4 sp = *(const float4*)(Lsp + bb * 64);
            a00 = fmaf(t2.x, sp.x, fmaf(g2.x, -sp.y, a00));
            a01 = fmaf(t2.x, sp.z, fmaf(g2.x, -sp.w, a01));
            a10 = fmaf(t2.y, sp.x, fmaf(g2.y, -sp.y, a10));
            a11 = fmaf(t2.y, sp.z, fmaf(g2.y, -sp.w, a11));
          }
        }
        __builtin_amdgcn_s_waitcnt(0xC07F);       // lgkmcnt(0) only
        __builtin_amdgcn_sched_barrier(0);
        __builtin_amdgcn_s_barrier();
        if (c < 5) SPSTG(c + 3, (c + 3) % 3);
      }
      #undef SPSTG

      // next-step tr/img prefetch streams in the epilogue + barrier shadow
      if (t + 1 < T_STEPS) {
        const float* imn = img + (size_t)(t + 1) * BATCH * INQ;
        #pragma unroll
        for (int q = 0; q < 8; ++q) {
          int br = q * 32 + p2w * 4 + (p2l >> 4);
          gl_lds16c(trN + (size_t)br * INQ + icol,
                    &stg_tr[(q * 32 + p2w * 4) * 64]);
          gl_lds16 (imn + (size_t)br * INQ + icol,
                    &stg_im[(q * 32 + p2w * 4) * 64]);
        }
      }
      if (active) {
        float2 wv;
        wv = wl0;
        wv.x = fminf(fmaxf(wv.x + 1e-3f * a00, 0.f), 1.f);
        wv.y = fminf(fmaxf(wv.y + 1e-3f * a01, 0.f), 1.f);
        st_coh2(Wt + (size_t)(ib + 0) * NP + nb, wv);
        wv = wl1;
        wv.x = fminf(fmaxf(wv.x + 1e-3f * a10, 0.f), 1.f);
        wv.y = fminf(fmaxf(wv.y + 1e-3f * a11, 0.f), 1.f);
        st_coh2(Wt + (size_t)(ib + 1) * NP + nb, wv);
      }
    }
    ++bt; gbar(barf, bt, blk);
  }

  // ---- final: W_out[n][i] = Wt[i][n] ----
  for (int e = blk * NTHR + tid; e < NOUT * INQ; e += GRID * NTHR) {
    int n = e / INQ, i = e % INQ;
    Wout[e] = ld_coh(Wt + (size_t)i * NP + n);
  }
}

extern "C" void kernel_launch(void* const* d_in, const int* in_sizes, int n_in,
                              void* d_out, int out_size, void* d_ws, size_t ws_size,
                              hipStream_t stream) {
  const float* img = (const float*)d_in[0];
  const float* W   = (const float*)d_in[1];
  float* out = (float*)d_out;
  float* ws  = (float*)d_ws;

  hipMemsetAsync(d_ws, 0, (size_t)WS_FLOATS * sizeof(float), stream);

  void* args[] = { (void*)&img, (void*)&W, (void*)&out, (void*)&ws };
  hipError_t rc = hipLaunchCooperativeKernel((const void*)snn_kernel,
                                             dim3(GRID), dim3(NTHR),
                                             args, 0, stream);
  if (rc != hipSuccess) {
    // Hand-rolled grid barrier; ~155 KB LDS -> 1 block/CU, grid == #CUs:
    // co-residency holds by construction under a plain launch.
    hipLaunchKernelGGL(snn_kernel, dim3(GRID), dim3(NTHR), 0, stream,
                       img, W, out, ws);
  }
}